// Round 9
// baseline (4816.203 us; speedup 1.0000x reference)
//
#include <hip/hip_runtime.h>
#include <math.h>

#define T_DIM 30
#define B_DIM 512
#define S_DIM 282          // H + UE + PE
#define NB (T_DIM*B_DIM)   // 15360 nodes / rows
#define E_DIM (NB*8)       // 122880 edges
#define G3 846             // 3*S
#define GST 2538           // fused gate row stride (3*846)
#define KXP 288            // padded K for S=282 and 266

typedef __attribute__((ext_vector_type(8))) short bf16x8;
typedef __attribute__((ext_vector_type(4))) float f32x4;

__device__ __forceinline__ float sigm(float x){ return 1.f/(1.f+expf(-x)); }

__device__ __forceinline__ ushort f2b(float f){
  union { float f; unsigned u; } v; v.f = f;
  unsigned r = v.u + 0x7fffu + ((v.u >> 16) & 1u);
  return (ushort)(r >> 16);
}
__device__ __forceinline__ float b2f(ushort b){
  union { unsigned u; float f; } v; v.u = ((unsigned)b) << 16; return v.f;
}
__device__ __forceinline__ void f2b2(float v, ushort& hi, ushort& lo){
  hi = f2b(v);
  lo = f2b(v - b2f(hi));
}

#define GLDS16(g, l) __builtin_amdgcn_global_load_lds( \
    (const __attribute__((address_space(1))) void*)(g), \
    (__attribute__((address_space(3))) void*)(l), 16, 0, 0)

// ---------------- split-bf16 MFMA GEMM, 128x128 tile ----------------
// A [M, 2*Kp] bf16 (hi plane +0, lo plane +Kp) staged via LDS (dbuf, swizzled);
// W [Npad, 2*Kp] read DIRECTLY from global (L2-resident, high reuse).
// C[M,ldc] f32 = act(A @ W^T + bias), cols < Nreal. 4 waves stacked in M.
// If xout != null, epilogue also writes split-bf16 into xout[row][2*KXP] cols<256.
__global__ __launch_bounds__(256, 4) void mfma_gemm4(
    const ushort* __restrict__ A, const ushort* __restrict__ W,
    const float* __restrict__ bias, float* __restrict__ C,
    int Nreal, int Kp, int ldc, int act, ushort* __restrict__ xout)
{
  __shared__ char smem[32768];   // [2 dbuf][A 16K]

  // XCD swizzle: keep all col-tiles of a row-panel on one XCD (A L2 reuse).
  int gx = gridDim.x;
  int h = blockIdx.y*gx + blockIdx.x;
  int nwg = gx*gridDim.y;
  int bx, by;
  if ((nwg & 7) == 0) {
    int q = nwg >> 3;
    int lwg = (h & 7)*q + (h >> 3);
    by = lwg / gx; bx = lwg - by*gx;
  } else { by = blockIdx.y; bx = blockIdx.x; }

  int tid  = threadIdx.x;
  int w    = tid >> 6;
  int lane = tid & 63;
  int lr = lane & 15;       // row (A) / col (B) within 16
  int lk = lane >> 4;       // k-octet 0..3
  int row0 = by*128;
  int col0 = bx*128;
  size_t astr = 2*(size_t)Kp;
  int NK = Kp >> 5;         // chunks of 32

  // stage A chunk kt into buffer buf (rows 0..127, both planes, 16 KB).
  // linear LDS dest + inverse-swizzled global source (rule: both-sides-or-neither).
  auto stageA = [&](int buf, int kt){
    int kk = kt*32;
    char* Ab = smem + buf*16384;
    #pragma unroll
    for (int i = 0; i < 4; ++i) {
      int sb = w*256 + i*64;         // wave-uniform slot base
      int s  = sb + lane;
      int r  = s >> 3;
      int rl = (s & 7) ^ (r & 7);
      int p  = rl >> 2, ks = rl & 3;
      const ushort* ga = A + (size_t)(row0 + r)*astr + (size_t)p*Kp + kk + ks*8;
      GLDS16(ga, Ab + sb*16);
    }
  };
  // swizzled LDS read: row r (block-relative), plane p, k-octet lk
  auto rdfrag = [&](char* base, int r, int p)->bf16x8{
    int byte = r*128 + (((p*64) + lk*16) ^ ((r & 7) << 4));
    return *reinterpret_cast<const bf16x8*>(base + byte);
  };

  f32x4 acc[2][8] = {};
  stageA(0, 0);
  __syncthreads();

  for (int kt = 0; kt < NK; ++kt) {
    int cur = kt & 1;
    if (kt + 1 < NK) stageA(cur ^ 1, kt + 1);   // async prefetch over compute
    char* Ab = smem + cur*16384;
    int kk = kt*32;

    bf16x8 a[2][2];
    #pragma unroll
    for (int i = 0; i < 2; ++i)
      #pragma unroll
      for (int p = 0; p < 2; ++p)
        a[i][p] = rdfrag(Ab, w*32 + i*16 + lr, p);

    #pragma unroll
    for (int j = 0; j < 8; ++j) {
      const ushort* wp = W + (size_t)(col0 + j*16 + lr)*astr + kk + lk*8;
      bf16x8 bh = *reinterpret_cast<const bf16x8*>(wp);
      bf16x8 bl = *reinterpret_cast<const bf16x8*>(wp + Kp);
      acc[0][j] = __builtin_amdgcn_mfma_f32_16x16x32_bf16(a[0][0], bh, acc[0][j], 0,0,0);
      acc[0][j] = __builtin_amdgcn_mfma_f32_16x16x32_bf16(a[0][1], bh, acc[0][j], 0,0,0);
      acc[0][j] = __builtin_amdgcn_mfma_f32_16x16x32_bf16(a[0][0], bl, acc[0][j], 0,0,0);
      acc[1][j] = __builtin_amdgcn_mfma_f32_16x16x32_bf16(a[1][0], bh, acc[1][j], 0,0,0);
      acc[1][j] = __builtin_amdgcn_mfma_f32_16x16x32_bf16(a[1][1], bh, acc[1][j], 0,0,0);
      acc[1][j] = __builtin_amdgcn_mfma_f32_16x16x32_bf16(a[1][0], bl, acc[1][j], 0,0,0);
    }
    __syncthreads();
  }

  #pragma unroll
  for (int i = 0; i < 2; ++i) {
    #pragma unroll
    for (int j = 0; j < 8; ++j) {
      int cc = col0 + j*16 + lr;
      if (cc >= Nreal) continue;
      float bv = bias[cc];
      #pragma unroll
      for (int r = 0; r < 4; ++r) {
        int rr = row0 + w*32 + i*16 + lk*4 + r;
        float v = acc[i][j][r] + bv;
        if (act) v = tanhf(v);
        C[(size_t)rr*ldc + cc] = v;
        if (xout && cc < 256) {
          ushort hi, lo; f2b2(v, hi, lo);
          xout[(size_t)rr*2*KXP + cc]       = hi;
          xout[(size_t)rr*2*KXP + KXP + cc] = lo;
        }
      }
    }
  }
}

static inline void mgemm4(const ushort* A, const ushort* W, const float* bias,
                          float* C, int Nreal, int Npad, int Kp, int ldc,
                          int act, ushort* xout, hipStream_t s)
{
  dim3 grid((Npad + 127)/128, NB/128);
  mfma_gemm4<<<grid, 256, 0, s>>>(A, W, bias, C, Nreal, Kp, ldc, act, xout);
}

// ---------------- cast weight [Nreal,K] f32 -> [Npad, 2*Kp] bf16 hi|lo, zero-padded ----------------
__global__ void cast_w(const float* __restrict__ w, ushort* __restrict__ wb,
                       int Nreal, int K, int Kp, int Npad)
{
  int idx = blockIdx.x*256 + threadIdx.x;
  if (idx >= Npad*Kp) return;
  int n = idx / Kp, k = idx - n*Kp;
  float v = (n < Nreal && k < K) ? w[(size_t)n*K + k] : 0.f;
  ushort hi, lo; f2b2(v, hi, lo);
  wb[(size_t)n*2*Kp + k]      = hi;
  wb[(size_t)n*2*Kp + Kp + k] = lo;
}
static inline void castw(const float* w, ushort* wb, int Nreal, int K, int Kp,
                         int Npad, hipStream_t s)
{
  int tot = Npad*Kp;
  cast_w<<<(tot+255)/256, 256, 0, s>>>(w, wb, Nreal, K, Kp, Npad);
}

// ---------------- all bias concats in one launch ----------------
__global__ void copy_bias(const float* __restrict__ c1_bih, const float* __restrict__ c1_bhh,
                          const float* __restrict__ c2_bhh, const float* __restrict__ bih_f,
                          const float* __restrict__ bih_b, const float* __restrict__ c2_bih,
                          float* __restrict__ bt, float* __restrict__ bx, float* __restrict__ b2)
{
  int i = blockIdx.x*256 + threadIdx.x;
  if (i < 846) {
    bt[i] = c1_bih[i]; bt[846+i] = c1_bhh[i]; bt[1692+i] = c2_bhh[i];
    b2[i] = c2_bih[i];
  }
  if (i < 768) { bx[i] = bih_f[i]; bx[768+i] = bih_b[i]; }
}

// ---------------- inp = concat(utter, ub) -> split bf16 [T*B, 2*288] ----------------
__global__ void build_inp(const float* __restrict__ utter, const float* __restrict__ ub,
                          ushort* __restrict__ inp)
{
  int r = blockIdx.x;
  for (int c = threadIdx.x; c < KXP; c += 128){
    float v = 0.f;
    if (c < 256)      v = utter[(size_t)r*256 + c];
    else if (c < 266) v = ub[(size_t)r*10 + (c-256)];
    ushort hi, lo; f2b2(v, hi, lo);
    inp[(size_t)r*2*KXP + c]       = hi;
    inp[(size_t)r*2*KXP + KXP + c] = lo;
  }
}

// ---------------- one GRU time step, both dirs; whh in NATIVE [768][256] layout ----------------
// block: 8 j x 32 dialogues; wt slice/block = 24 rows (24.5 KB, L1-friendly)
__global__ __launch_bounds__(256) void gru_step2(
    const float* __restrict__ gx,
    const float* __restrict__ whh_f, const float* __restrict__ bhh_f,
    const float* __restrict__ whh_b, const float* __restrict__ bhh_b,
    float* __restrict__ ys_f, float* __restrict__ ys_b, int t)
{
  int dir = blockIdx.z;
  const float* wh  = dir ? whh_b : whh_f;     // [768 j][256 k] row-major
  const float* bhh = dir ? bhh_b : bhh_f;
  float* ys = dir ? ys_b : ys_f;
  int tt = dir ? (T_DIM-1 - t) : t;
  const float* hprev = (t > 0) ? ys + (size_t)(dir ? tt+1 : tt-1)*B_DIM*256 : nullptr;

  int jg = threadIdx.x & 7;
  int bb = threadIdx.x >> 3;
  int j  = blockIdx.x*8 + jg;
  int b  = blockIdx.y*32 + bb;

  __shared__ float sh[32][260];   // pad 260: bank-spread + 16B-aligned rows
  for (int i = threadIdx.x; i < 32*256; i += 256) {
    int ib = i >> 8, kk = i & 255;
    int gb = blockIdx.y*32 + ib;
    sh[ib][kk] = hprev ? hprev[(size_t)gb*256 + kk] : 0.f;
  }
  __syncthreads();

  const float* wr = wh + (size_t)j*256;
  const float* wz = wh + (size_t)(256+j)*256;
  const float* wn = wh + (size_t)(512+j)*256;
  float ar = bhh[j], az = bhh[256+j], an = bhh[512+j];
  #pragma unroll 4
  for (int k = 0; k < 256; k += 4) {
    float4 h4 = *reinterpret_cast<const float4*>(&sh[bb][k]);
    float4 r4 = *reinterpret_cast<const float4*>(wr + k);
    float4 z4 = *reinterpret_cast<const float4*>(wz + k);
    float4 n4 = *reinterpret_cast<const float4*>(wn + k);
    ar += h4.x*r4.x + h4.y*r4.y + h4.z*r4.z + h4.w*r4.w;
    az += h4.x*z4.x + h4.y*z4.y + h4.z*z4.z + h4.w*z4.w;
    an += h4.x*n4.x + h4.y*n4.y + h4.z*n4.z + h4.w*n4.w;
  }
  size_t base = ((size_t)tt*B_DIM + b)*1536 + (size_t)dir*768;
  float r = sigm(gx[base + j]       + ar);
  float z = sigm(gx[base + 256 + j] + az);
  float n = tanhf(gx[base + 512 + j] + r*an);
  float h = sh[bb][j];
  ys[((size_t)tt*B_DIM + b)*256 + j] = (1.f - z)*n + z*h;
}

// ---------------- concat two f32 [M,256] into split bf16 [M, 2*512]; mapmode=1 remaps 2nd src ----------------
__global__ void build_cat(const float* __restrict__ a, const float* __restrict__ b2,
                          ushort* __restrict__ c, int mapmode)
{
  int r = blockIdx.x;
  int r2 = r;
  if (mapmode){ int t = r >> 9, bb = r & 511; r2 = bb*T_DIM + t; }
  for (int cix = threadIdx.x; cix < 512; cix += 128){
    float v = (cix < 256) ? a[(size_t)r*256 + cix] : b2[(size_t)r2*256 + (cix-256)];
    ushort hi, lo; f2b2(v, hi, lo);
    c[(size_t)r*1024 + cix]       = hi;
    c[(size_t)r*1024 + 512 + cix] = lo;
  }
}

// ---------------- xin[n] = [x_src, posemb, ub_flat] -> split bf16 [N, 2*288] ----------------
__global__ void build_xin(const float* __restrict__ xsrc, int reorder,
                          const float* __restrict__ posemb, const float* __restrict__ ub,
                          ushort* __restrict__ xin)
{
  int n = blockIdx.x;
  int b = n / T_DIM, t = n % T_DIM;
  int srow = reorder ? (t*B_DIM + b) : n;
  for (int s = threadIdx.x; s < KXP; s += 128){
    float v = 0.f;
    if (s < 256)      v = xsrc[(size_t)srow*256 + s];
    else if (s < 272) v = posemb[t*16 + (s-256)];
    else if (s < 282) v = ub[(size_t)n*10 + (s-272)];
    ushort hi, lo; f2b2(v, hi, lo);
    xin[(size_t)n*2*KXP + s]       = hi;
    xin[(size_t)n*2*KXP + KXP + s] = lo;
  }
}

// ---------------- edge message + aggregate; XCD node swizzle for L2 locality ----------------
__global__ __launch_bounds__(128) void edge_aggr(
    const float* __restrict__ gate, const ushort* __restrict__ xin,
    const int* __restrict__ esrc, const int* __restrict__ edst,
    const float* __restrict__ ew, ushort* __restrict__ aggr)
{
  int bid = blockIdx.x;
  int node = (bid & 7)*(NB/8) + (bid >> 3);   // dialogues confined to one XCD
  int e0 = node * 8;
  __shared__ int ssrc[8]; __shared__ float sw[8]; __shared__ int sdst;
  if (threadIdx.x < 8) { ssrc[threadIdx.x] = esrc[e0+threadIdx.x]; sw[threadIdx.x] = ew[e0+threadIdx.x]; }
  if (threadIdx.x == 0) sdst = edst[e0];
  __syncthreads();
  int i = sdst;
  for (int s = threadIdx.x; s < KXP; s += 128) {
    if (s >= S_DIM) {
      aggr[(size_t)i*2*KXP + s] = 0; aggr[(size_t)i*2*KXP + KXP + s] = 0; continue;
    }
    size_t gi = (size_t)i*GST;
    float hr = gate[gi + 846 + s];
    float hz = gate[gi + 1128 + s];
    float hn = gate[gi + 1410 + s];
    float hv = b2f(xin[(size_t)i*2*KXP + s]) + b2f(xin[(size_t)i*2*KXP + KXP + s]);
    float acc = 0.f;
    #pragma unroll
    for (int d = 0; d < 8; ++d) {
      size_t gj = (size_t)ssrc[d]*GST; float w = sw[d];
      float xr = gate[gj + s];
      float xz = gate[gj + 282 + s];
      float xn = gate[gj + 564 + s];
      float r = sigm(xr + hr);
      float z = sigm(xz + hz);
      float n = tanhf(xn + r*hn);
      acc += w * ((1.f - z)*n + z*hv);
    }
    ushort hi, lo; f2b2(acc, hi, lo);
    aggr[(size_t)i*2*KXP + s]       = hi;
    aggr[(size_t)i*2*KXP + KXP + s] = lo;
  }
}

// ---------------- GRUCell2 combine; g2x@846, g2h@1692 in fused gates ----------------
__global__ __launch_bounds__(128) void gru2_combine(
    const float* __restrict__ gate, const ushort* __restrict__ xin,
    ushort* __restrict__ upd)
{
  int n = blockIdx.x;
  for (int s = threadIdx.x; s < KXP; s += 128) {
    if (s >= S_DIM) {
      upd[(size_t)n*2*KXP + s] = 0; upd[(size_t)n*2*KXP + KXP + s] = 0; continue;
    }
    size_t g = (size_t)n*GST;
    float xr = gate[g + 846 + s];
    float xz = gate[g + 1128 + s];
    float xn = gate[g + 1410 + s];
    float hr = gate[g + 1692 + s];
    float hz = gate[g + 1974 + s];
    float hn = gate[g + 2256 + s];
    float h  = b2f(xin[(size_t)n*2*KXP + s]) + b2f(xin[(size_t)n*2*KXP + KXP + s]);
    float r = sigm(xr + hr);
    float z = sigm(xz + hz);
    float nn = tanhf(xn + r*hn);
    ushort hi, lo; f2b2((1.f - z)*nn + z*h, hi, lo);
    upd[(size_t)n*2*KXP + s]       = hi;
    upd[(size_t)n*2*KXP + KXP + s] = lo;
  }
}

// ---------------- xs = tanh(x1+x2+x3); LayerNorm over 256 ----------------
__global__ __launch_bounds__(256) void sum_ln(
    const float* __restrict__ x1, const float* __restrict__ x2, const float* __restrict__ x3,
    const float* __restrict__ g, const float* __restrict__ bta, float* __restrict__ out)
{
  int n = blockIdx.x; int j = threadIdx.x;
  size_t idx = (size_t)n*256 + j;
  float v = tanhf(x1[idx] + x2[idx] + x3[idx]);
  float s = v, sq = v*v;
  #pragma unroll
  for (int o = 32; o; o >>= 1) { s += __shfl_down(s, o, 64); sq += __shfl_down(sq, o, 64); }
  __shared__ float wsm[4], ws2[4];
  int lane = j & 63, w = j >> 6;
  if (lane == 0){ wsm[w] = s; ws2[w] = sq; }
  __syncthreads();
  float mean = (wsm[0]+wsm[1]+wsm[2]+wsm[3]) * (1.f/256.f);
  float m2   = (ws2[0]+ws2[1]+ws2[2]+ws2[3]) * (1.f/256.f);
  float var = m2 - mean*mean;
  float inv = rsqrtf(var + 1e-5f);
  out[idx] = g[j]*(v-mean)*inv + bta[j];
}

extern "C" void kernel_launch(void* const* d_in, const int* in_sizes, int n_in,
                              void* d_out, int out_size, void* d_ws, size_t ws_size,
                              hipStream_t stream)
{
  const float* utter = (const float*)d_in[0];
  const float* ub    = (const float*)d_in[1];
  const float* ew    = (const float*)d_in[2];
  const float* wih_f = (const float*)d_in[3];
  const float* whh_f = (const float*)d_in[4];
  const float* bih_f = (const float*)d_in[5];
  const float* bhh_f = (const float*)d_in[6];
  const float* wih_b = (const float*)d_in[7];
  const float* whh_b = (const float*)d_in[8];
  const float* bih_b = (const float*)d_in[9];
  const float* bhh_b = (const float*)d_in[10];
  const float* lin1_w= (const float*)d_in[11];
  const float* lin1_b= (const float*)d_in[12];
  const float* posemb= (const float*)d_in[13];
  const float* c1_wih= (const float*)d_in[14];
  const float* c1_whh= (const float*)d_in[15];
  const float* c1_bih= (const float*)d_in[16];
  const float* c1_bhh= (const float*)d_in[17];
  const float* c2_wih= (const float*)d_in[18];
  const float* c2_whh= (const float*)d_in[19];
  const float* c2_bih= (const float*)d_in[20];
  const float* c2_bhh= (const float*)d_in[21];
  const float* gw[3] = {(const float*)d_in[22], (const float*)d_in[24], (const float*)d_in[26]};
  const float* gb[3] = {(const float*)d_in[23], (const float*)d_in[25], (const float*)d_in[27]};
  const float* ln_g  = (const float*)d_in[28];
  const float* ln_b  = (const float*)d_in[29];
  const float* lin2_w= (const float*)d_in[30];
  const float* lin2_b= (const float*)d_in[31];
  const int*   eidx  = (const int*)d_in[32];
  const int* esrc = eidx;
  const int* edst = eidx + E_DIM;
  (void)ws_size; (void)n_in; (void)in_sizes; (void)out_size;

  float* ws = (float*)d_ws;
  size_t o = 0;
  auto A  = [&](size_t n){ size_t r = o; o += (n+3)&~(size_t)3; return r; };  // floats, 16B-align
  auto AU = [&](size_t n){ return A((n+1)/2); };                              // ushorts

  // float buffers
  size_t bGATE = A((size_t)NB*GST);   // fused gates; also hosts gx(ldc1536), uCAT, x3
  size_t bYF   = A((size_t)NB*256);   // ys_f | x1 | LN-out ; uINP alias (spans into bYB/bRNN)
  size_t bYB   = A((size_t)NB*256);   // ys_b | x2
  size_t bRNN  = A((size_t)NB*256);   // rnn_x
  size_t bBT   = A(2560);             // triple bias [c1_bih|c1_bhh|c2_bhh]
  size_t bBX   = A(1536);             // xproj bias [bih_f|bih_b]
  size_t bB2   = A(896);              // g2x bias [c2_bih]
  // bf16 split buffers
  size_t uXIN = AU((size_t)NB*2*KXP);
  size_t uAGG = AU((size_t)NB*2*KXP);
  size_t uWC1 = AU((size_t)2560*2*KXP);   // [c1_wih|c1_whh|c2_whh|pad]
  size_t uWXP = AU((size_t)1536*2*KXP);   // [wih_f|wih_b]
  size_t uW2X = AU((size_t)896*2*KXP);    // c2_wih
  size_t uG0  = AU((size_t)256*2*KXP);
  size_t uG1  = AU((size_t)256*2*KXP);
  size_t uG2  = AU((size_t)256*2*KXP);
  size_t uL1  = AU((size_t)256*2*512);
  size_t uL2  = AU((size_t)256*2*512);

  ushort* us = (ushort*)d_ws;
  auto U = [&](size_t fo){ return us + fo*2; };
  float* gate = ws + bGATE;
  ushort* uINP  = (ushort*)(ws + bYF);      // [NB, 2*288] spans bYF.. (dead before ys written)
  ushort* uCAT  = (ushort*)gate;            // cat1/cat2 (region dead at use time)
  float*  x3    = gate;                     // layer-3 output (gates dead at write time)

  // --- weight casts (split bf16, padded) ---
  castw(wih_f,  U(uWXP),                       768, 266,  KXP, 768, stream);
  castw(wih_b,  U(uWXP) + (size_t)768*2*KXP,   768, 266,  KXP, 768, stream);
  castw(c1_wih, U(uWC1),                       846, S_DIM, KXP, 846, stream);
  castw(c1_whh, U(uWC1) + (size_t)846*2*KXP,   846, S_DIM, KXP, 846, stream);
  castw(c2_whh, U(uWC1) + (size_t)1692*2*KXP,  846, S_DIM, KXP, 868, stream);  // pads to 2560
  castw(c2_wih, U(uW2X),                       846, S_DIM, KXP, 896, stream);
  castw(gw[0],  U(uG0), 256, S_DIM, KXP, 256, stream);
  castw(gw[1],  U(uG1), 256, S_DIM, KXP, 256, stream);
  castw(gw[2],  U(uG2), 256, S_DIM, KXP, 256, stream);
  castw(lin1_w, U(uL1), 256, 512, 512, 256, stream);
  castw(lin2_w, U(uL2), 256, 512, 512, 256, stream);
  const ushort* uGW[3] = {U(uG0), U(uG1), U(uG2)};
  copy_bias<<<4, 256, 0, stream>>>(c1_bih, c1_bhh, c2_bhh, bih_f, bih_b, c2_bih,
                                   ws+bBT, ws+bBX, ws+bB2);

  // --- RNN phase ---
  build_inp<<<NB, 128, 0, stream>>>(utter, ub, uINP);
  mgemm4(uINP, U(uWXP), ws+bBX, gate, 1536, 1536, KXP, 1536, 0, nullptr, stream);  // gx fused
  for (int t = 0; t < T_DIM; ++t)
    gru_step2<<<dim3(32,16,2), 256, 0, stream>>>(gate, whh_f, bhh_f, whh_b, bhh_b,
                                                 ws+bYF, ws+bYB, t);
  build_cat<<<NB, 128, 0, stream>>>(ws+bYF, ws+bYB, uCAT, 0);
  mgemm4(uCAT, U(uL1), lin1_b, ws+bRNN, 256, 256, 512, 256, 1, nullptr, stream);

  // --- conv layers ---
  build_xin<<<NB, 128, 0, stream>>>(ws+bRNN, 1, posemb, ub, U(uXIN));
  float* XL[3] = {ws+bYF, ws+bYB, x3};
  for (int l = 0; l < 3; ++l) {
    // fused triple: g1x | g1h | g2h  (all read xin)
    mgemm4(U(uXIN), U(uWC1), ws+bBT, gate, 2538, 2560, KXP, GST, 0, nullptr, stream);
    edge_aggr<<<NB, 128, 0, stream>>>(gate, U(uXIN), esrc, edst, ew, U(uAGG));
    // g2x = aggr @ c2_wih -> overwrite g1h slot (cols [846,1692))
    mgemm4(U(uAGG), U(uW2X), ws+bB2, gate + 846, 846, 896, KXP, GST, 0, nullptr, stream);
    gru2_combine<<<NB, 128, 0, stream>>>(gate, U(uXIN), U(uAGG));
    // out-GEMM; for l<2 epilogue also refreshes xin cols 0..255 (pos/ub cols persist)
    mgemm4(U(uAGG), uGW[l], gb[l], XL[l], 256, 256, KXP, 256, 1,
           (l < 2) ? U(uXIN) : nullptr, stream);
  }

  // --- epilogue ---
  sum_ln<<<NB, 256, 0, stream>>>(XL[0], XL[1], XL[2], ln_g, ln_b, ws+bYF);  // in-place on x1
  build_cat<<<NB, 128, 0, stream>>>(ws+bRNN, ws+bYF, uCAT, 1);
  mgemm4(uCAT, U(uL2), lin2_b, (float*)d_out, 256, 256, 512, 256, 1, nullptr, stream);
}

// Round 11
// 1826.332 us; speedup vs baseline: 2.6371x; 2.6371x over previous
//
#include <hip/hip_runtime.h>
#include <math.h>

#define T_DIM 30
#define B_DIM 512
#define S_DIM 282          // H + UE + PE
#define NB (T_DIM*B_DIM)   // 15360 nodes / rows
#define E_DIM (NB*8)       // 122880 edges
#define G3 846             // 3*S
#define GST 2538           // fused gate row stride (3*846)
#define KXP 288            // padded K for S=282 and 266

typedef __attribute__((ext_vector_type(8))) short bf16x8;
typedef __attribute__((ext_vector_type(4))) float f32x4;

__device__ __forceinline__ float sigm(float x){ return 1.f/(1.f+expf(-x)); }

__device__ __forceinline__ ushort f2b(float f){
  union { float f; unsigned u; } v; v.f = f;
  unsigned r = v.u + 0x7fffu + ((v.u >> 16) & 1u);
  return (ushort)(r >> 16);
}
__device__ __forceinline__ float b2f(ushort b){
  union { unsigned u; float f; } v; v.u = ((unsigned)b) << 16; return v.f;
}
__device__ __forceinline__ void f2b2(float v, ushort& hi, ushort& lo){
  hi = f2b(v);
  lo = f2b(v - b2f(hi));
}

#define GLDS16(g, l) __builtin_amdgcn_global_load_lds( \
    (const __attribute__((address_space(1))) void*)(g), \
    (__attribute__((address_space(3))) void*)(l), 16, 0, 0)

// ---------------- split-bf16 MFMA GEMM, 128x128 tile, LDS-staged dbuf ----------------
// (round-8 proven form: BOTH operands staged through LDS, 64K dbuf, swizzled)
// A [M, 2*Kp] bf16 (hi plane +0, lo plane +Kp), W [Npad, 2*Kp] same layout.
// C[M,ldc] f32 = act(A @ W^T + bias), cols < Nreal. 4 waves stacked in M.
// If xout != null, epilogue also writes split-bf16 into xout[row][2*KXP] cols<256.
__global__ __launch_bounds__(256, 2) void mfma_gemm3(
    const ushort* __restrict__ A, const ushort* __restrict__ W,
    const float* __restrict__ bias, float* __restrict__ C,
    int Nreal, int Kp, int ldc, int act, ushort* __restrict__ xout)
{
  __shared__ char smem[65536];   // [2 dbuf][A 16K | W 16K]

  // XCD swizzle: keep all col-tiles of a row-panel on one XCD (A L2 reuse).
  int gx = gridDim.x;
  int h = blockIdx.y*gx + blockIdx.x;
  int nwg = gx*gridDim.y;
  int bx, by;
  if ((nwg & 7) == 0) {
    int q = nwg >> 3;
    int lwg = (h & 7)*q + (h >> 3);
    by = lwg / gx; bx = lwg - by*gx;
  } else { by = blockIdx.y; bx = blockIdx.x; }

  int tid  = threadIdx.x;
  int w    = tid >> 6;
  int lane = tid & 63;
  int lr = lane & 15;       // row (A) / col (B) within 16
  int lk = lane >> 4;       // k-octet 0..3
  int row0 = by*128;
  int col0 = bx*128;
  size_t astr = 2*(size_t)Kp;
  int NK = Kp >> 5;         // chunks of 32

  // stage chunk kt: linear LDS dest + inverse-swizzled global source.
  auto stage = [&](int buf, int kt){
    int kk = kt*32;
    char* Ab = smem + buf*32768;
    char* Wb = Ab + 16384;
    #pragma unroll
    for (int i = 0; i < 4; ++i) {
      int sb = w*256 + i*64;         // wave-uniform slot base
      int s  = sb + lane;
      int r  = s >> 3;
      int rl = (s & 7) ^ (r & 7);
      int p  = rl >> 2, ks = rl & 3;
      const ushort* ga = A + (size_t)(row0 + r)*astr + (size_t)p*Kp + kk + ks*8;
      GLDS16(ga, Ab + sb*16);
      const ushort* gw = W + (size_t)(col0 + r)*astr + (size_t)p*Kp + kk + ks*8;
      GLDS16(gw, Wb + sb*16);
    }
  };
  auto rdfrag = [&](char* base, int r, int p)->bf16x8{
    int byte = r*128 + (((p*64) + lk*16) ^ ((r & 7) << 4));
    return *reinterpret_cast<const bf16x8*>(base + byte);
  };

  f32x4 acc[2][8] = {};
  stage(0, 0);
  __syncthreads();

  for (int kt = 0; kt < NK; ++kt) {
    int cur = kt & 1;
    if (kt + 1 < NK) stage(cur ^ 1, kt + 1);   // async prefetch over compute
    char* Ab = smem + cur*32768;
    char* Wb = Ab + 16384;

    bf16x8 a[2][2], b[8][2];
    #pragma unroll
    for (int i = 0; i < 2; ++i)
      #pragma unroll
      for (int p = 0; p < 2; ++p)
        a[i][p] = rdfrag(Ab, w*32 + i*16 + lr, p);
    #pragma unroll
    for (int j = 0; j < 8; ++j)
      #pragma unroll
      for (int p = 0; p < 2; ++p)
        b[j][p] = rdfrag(Wb, j*16 + lr, p);

    #pragma unroll
    for (int j = 0; j < 8; ++j) {
      acc[0][j] = __builtin_amdgcn_mfma_f32_16x16x32_bf16(a[0][0], b[j][0], acc[0][j], 0,0,0);
      acc[0][j] = __builtin_amdgcn_mfma_f32_16x16x32_bf16(a[0][1], b[j][0], acc[0][j], 0,0,0);
      acc[0][j] = __builtin_amdgcn_mfma_f32_16x16x32_bf16(a[0][0], b[j][1], acc[0][j], 0,0,0);
      acc[1][j] = __builtin_amdgcn_mfma_f32_16x16x32_bf16(a[1][0], b[j][0], acc[1][j], 0,0,0);
      acc[1][j] = __builtin_amdgcn_mfma_f32_16x16x32_bf16(a[1][1], b[j][0], acc[1][j], 0,0,0);
      acc[1][j] = __builtin_amdgcn_mfma_f32_16x16x32_bf16(a[1][0], b[j][1], acc[1][j], 0,0,0);
    }
    __syncthreads();
  }

  #pragma unroll
  for (int i = 0; i < 2; ++i) {
    #pragma unroll
    for (int j = 0; j < 8; ++j) {
      int cc = col0 + j*16 + lr;
      if (cc >= Nreal) continue;
      float bv = bias[cc];
      #pragma unroll
      for (int r = 0; r < 4; ++r) {
        int rr = row0 + w*32 + i*16 + lk*4 + r;
        float v = acc[i][j][r] + bv;
        if (act) v = tanhf(v);
        C[(size_t)rr*ldc + cc] = v;
        if (xout && cc < 256) {
          ushort hi, lo; f2b2(v, hi, lo);
          xout[(size_t)rr*2*KXP + cc]       = hi;
          xout[(size_t)rr*2*KXP + KXP + cc] = lo;
        }
      }
    }
  }
}

static inline void mgemm3(const ushort* A, const ushort* W, const float* bias,
                          float* C, int Nreal, int Npad, int Kp, int ldc,
                          int act, ushort* xout, hipStream_t s)
{
  dim3 grid((Npad + 127)/128, NB/128);
  mfma_gemm3<<<grid, 256, 0, s>>>(A, W, bias, C, Nreal, Kp, ldc, act, xout);
}

// ---------------- cast weight [Nreal,K] f32 -> [Npad, 2*Kp] bf16 hi|lo, zero-padded ----------------
__global__ void cast_w(const float* __restrict__ w, ushort* __restrict__ wb,
                       int Nreal, int K, int Kp, int Npad)
{
  int idx = blockIdx.x*256 + threadIdx.x;
  if (idx >= Npad*Kp) return;
  int n = idx / Kp, k = idx - n*Kp;
  float v = (n < Nreal && k < K) ? w[(size_t)n*K + k] : 0.f;
  ushort hi, lo; f2b2(v, hi, lo);
  wb[(size_t)n*2*Kp + k]      = hi;
  wb[(size_t)n*2*Kp + Kp + k] = lo;
}
static inline void castw(const float* w, ushort* wb, int Nreal, int K, int Kp,
                         int Npad, hipStream_t s)
{
  int tot = Npad*Kp;
  cast_w<<<(tot+255)/256, 256, 0, s>>>(w, wb, Nreal, K, Kp, Npad);
}

// ---------------- all bias concats in one launch ----------------
__global__ void copy_bias(const float* __restrict__ c1_bih, const float* __restrict__ c1_bhh,
                          const float* __restrict__ c2_bhh, const float* __restrict__ bih_f,
                          const float* __restrict__ bih_b, const float* __restrict__ c2_bih,
                          float* __restrict__ bt, float* __restrict__ bx, float* __restrict__ b2)
{
  int i = blockIdx.x*256 + threadIdx.x;
  if (i < 846) {
    bt[i] = c1_bih[i]; bt[846+i] = c1_bhh[i]; bt[1692+i] = c2_bhh[i];
    b2[i] = c2_bih[i];
  }
  if (i < 768) { bx[i] = bih_f[i]; bx[768+i] = bih_b[i]; }
}

// ---------------- transpose whh [768,256] -> [256,768] ----------------
__global__ void transpose_whh(const float* __restrict__ w, float* __restrict__ wt)
{
  int idx = blockIdx.x*256 + threadIdx.x;
  if (idx < 768*256) { int r = idx >> 8, c = idx & 255; wt[c*768 + r] = w[idx]; }
}

// ---------------- inp = concat(utter, ub) -> split bf16 [T*B, 2*288] ----------------
__global__ void build_inp(const float* __restrict__ utter, const float* __restrict__ ub,
                          ushort* __restrict__ inp)
{
  int r = blockIdx.x;
  for (int c = threadIdx.x; c < KXP; c += 128){
    float v = 0.f;
    if (c < 256)      v = utter[(size_t)r*256 + c];
    else if (c < 266) v = ub[(size_t)r*10 + (c-256)];
    ushort hi, lo; f2b2(v, hi, lo);
    inp[(size_t)r*2*KXP + c]       = hi;
    inp[(size_t)r*2*KXP + KXP + c] = lo;
  }
}

// ---------------- one GRU time step, both dirs; 2 dialogues per thread ----------------
// wt [256 k][768 j] (k-major transposed); gx fused [T*B, 1536]
__global__ __launch_bounds__(256) void gru_step(
    const float* __restrict__ gx,
    const float* __restrict__ wtf, const float* __restrict__ bhh_f,
    const float* __restrict__ wtb, const float* __restrict__ bhh_b,
    float* __restrict__ ys_f, float* __restrict__ ys_b, int t)
{
  int dir = blockIdx.z;
  const float* wt  = dir ? wtb  : wtf;
  const float* bhh = dir ? bhh_b : bhh_f;
  float* ys = dir ? ys_b : ys_f;
  int tt = dir ? (T_DIM-1 - t) : t;
  const float* hprev = (t > 0) ? ys + (size_t)(dir ? tt+1 : tt-1)*B_DIM*256 : nullptr;

  int tx = threadIdx.x & 63;   // j sub-index
  int ty = threadIdx.x >> 6;   // dialogue-pair id 0..3
  int j = blockIdx.x * 64 + tx;
  int b0 = blockIdx.y * 8 + ty*2;

  __shared__ float sh[8][256];
  for (int i = threadIdx.x; i < 8*256; i += 256) {
    int bb = i >> 8, kk = i & 255;
    int gb = blockIdx.y*8 + bb;
    sh[bb][kk] = hprev ? hprev[(size_t)gb*256 + kk] : 0.f;
  }
  __syncthreads();

  float ar0 = bhh[j], az0 = bhh[256+j], an0 = bhh[512+j];
  float ar1 = ar0, az1 = az0, an1 = an0;
  const float* h0p = sh[ty*2];
  const float* h1p = sh[ty*2+1];
  for (int k = 0; k < 256; ++k) {
    const float* wk = wt + (size_t)k*768;
    float wr = wk[j], wz = wk[256+j], wn = wk[512+j];
    float h0 = h0p[k], h1 = h1p[k];
    ar0 += h0*wr; az0 += h0*wz; an0 += h0*wn;
    ar1 += h1*wr; az1 += h1*wz; an1 += h1*wn;
  }
  #pragma unroll
  for (int bb = 0; bb < 2; ++bb) {
    int b = b0 + bb;
    size_t base = ((size_t)tt*B_DIM + b)*1536 + (size_t)dir*768;
    float ar = bb ? ar1 : ar0, az = bb ? az1 : az0, an = bb ? an1 : an0;
    float r = sigm(gx[base + j]       + ar);
    float z = sigm(gx[base + 256 + j] + az);
    float n = tanhf(gx[base + 512 + j] + r*an);
    float h = sh[ty*2+bb][j];
    ys[((size_t)tt*B_DIM + b)*256 + j] = (1.f - z)*n + z*h;
  }
}

// ---------------- concat two f32 [M,256] into split bf16 [M, 2*512]; mapmode=1 remaps 2nd src ----------------
__global__ void build_cat(const float* __restrict__ a, const float* __restrict__ b2,
                          ushort* __restrict__ c, int mapmode)
{
  int r = blockIdx.x;
  int r2 = r;
  if (mapmode){ int t = r >> 9, bb = r & 511; r2 = bb*T_DIM + t; }
  for (int cix = threadIdx.x; cix < 512; cix += 128){
    float v = (cix < 256) ? a[(size_t)r*256 + cix] : b2[(size_t)r2*256 + (cix-256)];
    ushort hi, lo; f2b2(v, hi, lo);
    c[(size_t)r*1024 + cix]       = hi;
    c[(size_t)r*1024 + 512 + cix] = lo;
  }
}

// ---------------- xin[n] = [x_src, posemb, ub_flat] -> split bf16 [N, 2*288] ----------------
__global__ void build_xin(const float* __restrict__ xsrc, int reorder,
                          const float* __restrict__ posemb, const float* __restrict__ ub,
                          ushort* __restrict__ xin)
{
  int n = blockIdx.x;
  int b = n / T_DIM, t = n % T_DIM;
  int srow = reorder ? (t*B_DIM + b) : n;
  for (int s = threadIdx.x; s < KXP; s += 128){
    float v = 0.f;
    if (s < 256)      v = xsrc[(size_t)srow*256 + s];
    else if (s < 272) v = posemb[t*16 + (s-256)];
    else if (s < 282) v = ub[(size_t)n*10 + (s-272)];
    ushort hi, lo; f2b2(v, hi, lo);
    xin[(size_t)n*2*KXP + s]       = hi;
    xin[(size_t)n*2*KXP + KXP + s] = lo;
  }
}

// ---------------- edge message + aggregate; XCD node swizzle (64 dialogues/XCD) ----------------
__global__ __launch_bounds__(128) void edge_aggr(
    const float* __restrict__ gate, const ushort* __restrict__ xin,
    const int* __restrict__ esrc, const int* __restrict__ edst,
    const float* __restrict__ ew, ushort* __restrict__ aggr)
{
  int bid = blockIdx.x;
  int node = (bid & 7)*(NB/8) + (bid >> 3);   // dialogues confined to one XCD
  int e0 = node * 8;
  __shared__ int ssrc[8]; __shared__ float sw[8]; __shared__ int sdst;
  if (threadIdx.x < 8) { ssrc[threadIdx.x] = esrc[e0+threadIdx.x]; sw[threadIdx.x] = ew[e0+threadIdx.x]; }
  if (threadIdx.x == 0) sdst = edst[e0];
  __syncthreads();
  int i = sdst;
  for (int s = threadIdx.x; s < KXP; s += 128) {
    if (s >= S_DIM) {
      aggr[(size_t)i*2*KXP + s] = 0; aggr[(size_t)i*2*KXP + KXP + s] = 0; continue;
    }
    size_t gi = (size_t)i*GST;
    float hr = gate[gi + 846 + s];
    float hz = gate[gi + 1128 + s];
    float hn = gate[gi + 1410 + s];
    float hv = b2f(xin[(size_t)i*2*KXP + s]) + b2f(xin[(size_t)i*2*KXP + KXP + s]);
    float acc = 0.f;
    #pragma unroll
    for (int d = 0; d < 8; ++d) {
      size_t gj = (size_t)ssrc[d]*GST; float w = sw[d];
      float xr = gate[gj + s];
      float xz = gate[gj + 282 + s];
      float xn = gate[gj + 564 + s];
      float r = sigm(xr + hr);
      float z = sigm(xz + hz);
      float n = tanhf(xn + r*hn);
      acc += w * ((1.f - z)*n + z*hv);
    }
    ushort hi, lo; f2b2(acc, hi, lo);
    aggr[(size_t)i*2*KXP + s]       = hi;
    aggr[(size_t)i*2*KXP + KXP + s] = lo;
  }
}

// ---------------- GRUCell2 combine; g2x@846, g2h@1692 in fused gates ----------------
__global__ __launch_bounds__(128) void gru2_combine(
    const float* __restrict__ gate, const ushort* __restrict__ xin,
    ushort* __restrict__ upd)
{
  int n = blockIdx.x;
  for (int s = threadIdx.x; s < KXP; s += 128) {
    if (s >= S_DIM) {
      upd[(size_t)n*2*KXP + s] = 0; upd[(size_t)n*2*KXP + KXP + s] = 0; continue;
    }
    size_t g = (size_t)n*GST;
    float xr = gate[g + 846 + s];
    float xz = gate[g + 1128 + s];
    float xn = gate[g + 1410 + s];
    float hr = gate[g + 1692 + s];
    float hz = gate[g + 1974 + s];
    float hn = gate[g + 2256 + s];
    float h  = b2f(xin[(size_t)n*2*KXP + s]) + b2f(xin[(size_t)n*2*KXP + KXP + s]);
    float r = sigm(xr + hr);
    float z = sigm(xz + hz);
    float nn = tanhf(xn + r*hn);
    ushort hi, lo; f2b2((1.f - z)*nn + z*h, hi, lo);
    upd[(size_t)n*2*KXP + s]       = hi;
    upd[(size_t)n*2*KXP + KXP + s] = lo;
  }
}

// ---------------- xs = tanh(x1+x2+x3); LayerNorm over 256 ----------------
__global__ __launch_bounds__(256) void sum_ln(
    const float* __restrict__ x1, const float* __restrict__ x2, const float* __restrict__ x3,
    const float* __restrict__ g, const float* __restrict__ bta, float* __restrict__ out)
{
  int n = blockIdx.x; int j = threadIdx.x;
  size_t idx = (size_t)n*256 + j;
  float v = tanhf(x1[idx] + x2[idx] + x3[idx]);
  float s = v, sq = v*v;
  #pragma unroll
  for (int o = 32; o; o >>= 1) { s += __shfl_down(s, o, 64); sq += __shfl_down(sq, o, 64); }
  __shared__ float wsm[4], ws2[4];
  int lane = j & 63, w = j >> 6;
  if (lane == 0){ wsm[w] = s; ws2[w] = sq; }
  __syncthreads();
  float mean = (wsm[0]+wsm[1]+wsm[2]+wsm[3]) * (1.f/256.f);
  float m2   = (ws2[0]+ws2[1]+ws2[2]+ws2[3]) * (1.f/256.f);
  float var = m2 - mean*mean;
  float inv = rsqrtf(var + 1e-5f);
  out[idx] = g[j]*(v-mean)*inv + bta[j];
}

extern "C" void kernel_launch(void* const* d_in, const int* in_sizes, int n_in,
                              void* d_out, int out_size, void* d_ws, size_t ws_size,
                              hipStream_t stream)
{
  const float* utter = (const float*)d_in[0];
  const float* ub    = (const float*)d_in[1];
  const float* ew    = (const float*)d_in[2];
  const float* wih_f = (const float*)d_in[3];
  const float* whh_f = (const float*)d_in[4];
  const float* bih_f = (const float*)d_in[5];
  const float* bhh_f = (const float*)d_in[6];
  const float* wih_b = (const float*)d_in[7];
  const float* whh_b = (const float*)d_in[8];
  const float* bih_b = (const float*)d_in[9];
  const float* bhh_b = (const float*)d_in[10];
  const float* lin1_w= (const float*)d_in[11];
  const float* lin1_b= (const float*)d_in[12];
  const float* posemb= (const float*)d_in[13];
  const float* c1_wih= (const float*)d_in[14];
  const float* c1_whh= (const float*)d_in[15];
  const float* c1_bih= (const float*)d_in[16];
  const float* c1_bhh= (const float*)d_in[17];
  const float* c2_wih= (const float*)d_in[18];
  const float* c2_whh= (const float*)d_in[19];
  const float* c2_bih= (const float*)d_in[20];
  const float* c2_bhh= (const float*)d_in[21];
  const float* gw[3] = {(const float*)d_in[22], (const float*)d_in[24], (const float*)d_in[26]};
  const float* gb[3] = {(const float*)d_in[23], (const float*)d_in[25], (const float*)d_in[27]};
  const float* ln_g  = (const float*)d_in[28];
  const float* ln_b  = (const float*)d_in[29];
  const float* lin2_w= (const float*)d_in[30];
  const float* lin2_b= (const float*)d_in[31];
  const int*   eidx  = (const int*)d_in[32];
  const int* esrc = eidx;
  const int* edst = eidx + E_DIM;
  (void)ws_size; (void)n_in; (void)in_sizes; (void)out_size;

  float* ws = (float*)d_ws;
  size_t o = 0;
  auto A  = [&](size_t n){ size_t r = o; o += (n+3)&~(size_t)3; return r; };  // floats, 16B-align
  auto AU = [&](size_t n){ return A((n+1)/2); };                              // ushorts

  // float buffers
  size_t bGATE = A((size_t)NB*GST);   // fused gates; also hosts gx(ldc1536), wt's, uCAT, x3
  size_t bYF   = A((size_t)NB*256);   // ys_f | x1 | LN-out ; uINP alias (spans into bYB/bRNN)
  size_t bYB   = A((size_t)NB*256);   // ys_b | x2
  size_t bRNN  = A((size_t)NB*256);   // rnn_x
  size_t bBT   = A(2560);             // triple bias [c1_bih|c1_bhh|c2_bhh]
  size_t bBX   = A(1536);             // xproj bias [bih_f|bih_b]
  size_t bB2   = A(896);              // g2x bias [c2_bih]
  // bf16 split buffers
  size_t uXIN = AU((size_t)NB*2*KXP);
  size_t uAGG = AU((size_t)NB*2*KXP);
  size_t uWC1 = AU((size_t)2560*2*KXP);   // [c1_wih|c1_whh|c2_whh|pad]
  size_t uWXP = AU((size_t)1536*2*KXP);   // [wih_f|wih_b]
  size_t uW2X = AU((size_t)896*2*KXP);    // c2_wih
  size_t uG0  = AU((size_t)256*2*KXP);
  size_t uG1  = AU((size_t)256*2*KXP);
  size_t uG2  = AU((size_t)256*2*KXP);
  size_t uL1  = AU((size_t)256*2*512);
  size_t uL2  = AU((size_t)256*2*512);

  ushort* us = (ushort*)d_ws;
  auto U = [&](size_t fo){ return us + fo*2; };
  float* gate = ws + bGATE;
  // aliases inside bGATE (gx compact [NB,1536] = 23,592,960 floats)
  float* wtf = gate + 23592960;             // [256,768] transposed whh_f
  float* wtb = wtf + 196608;
  ushort* uINP  = (ushort*)(ws + bYF);      // [NB, 2*288] (dead before ys written)
  ushort* uCAT  = (ushort*)gate;            // cat1/cat2 (region dead at use time)
  float*  x3    = gate;                     // layer-3 output (gates dead at write time)

  // --- weight casts (split bf16, padded) ---
  castw(wih_f,  U(uWXP),                       768, 266,  KXP, 768, stream);
  castw(wih_b,  U(uWXP) + (size_t)768*2*KXP,   768, 266,  KXP, 768, stream);
  castw(c1_wih, U(uWC1),                       846, S_DIM, KXP, 846, stream);
  castw(c1_whh, U(uWC1) + (size_t)846*2*KXP,   846, S_DIM, KXP, 846, stream);
  castw(c2_whh, U(uWC1) + (size_t)1692*2*KXP,  846, S_DIM, KXP, 868, stream);  // pads to 2560
  castw(c2_wih, U(uW2X),                       846, S_DIM, KXP, 896, stream);
  castw(gw[0],  U(uG0), 256, S_DIM, KXP, 256, stream);
  castw(gw[1],  U(uG1), 256, S_DIM, KXP, 256, stream);
  castw(gw[2],  U(uG2), 256, S_DIM, KXP, 256, stream);
  castw(lin1_w, U(uL1), 256, 512, 512, 256, stream);
  castw(lin2_w, U(uL2), 256, 512, 512, 256, stream);
  const ushort* uGW[3] = {U(uG0), U(uG1), U(uG2)};
  copy_bias<<<4, 256, 0, stream>>>(c1_bih, c1_bhh, c2_bhh, bih_f, bih_b, c2_bih,
                                   ws+bBT, ws+bBX, ws+bB2);

  // --- RNN phase ---
  transpose_whh<<<(768*256+255)/256, 256, 0, stream>>>(whh_f, wtf);
  transpose_whh<<<(768*256+255)/256, 256, 0, stream>>>(whh_b, wtb);
  build_inp<<<NB, 128, 0, stream>>>(utter, ub, uINP);
  mgemm3(uINP, U(uWXP), ws+bBX, gate, 1536, 1536, KXP, 1536, 0, nullptr, stream);  // gx fused
  for (int t = 0; t < T_DIM; ++t)
    gru_step<<<dim3(4,64,2), 256, 0, stream>>>(gate, wtf, bhh_f, wtb, bhh_b,
                                               ws+bYF, ws+bYB, t);
  build_cat<<<NB, 128, 0, stream>>>(ws+bYF, ws+bYB, uCAT, 0);
  mgemm3(uCAT, U(uL1), lin1_b, ws+bRNN, 256, 256, 512, 256, 1, nullptr, stream);

  // --- conv layers ---
  build_xin<<<NB, 128, 0, stream>>>(ws+bRNN, 1, posemb, ub, U(uXIN));
  float* XL[3] = {ws+bYF, ws+bYB, x3};
  for (int l = 0; l < 3; ++l) {
    // fused triple: g1x | g1h | g2h  (all read xin)
    mgemm3(U(uXIN), U(uWC1), ws+bBT, gate, 2538, 2560, KXP, GST, 0, nullptr, stream);
    edge_aggr<<<NB, 128, 0, stream>>>(gate, U(uXIN), esrc, edst, ew, U(uAGG));
    // g2x = aggr @ c2_wih -> overwrite g1h slot (cols [846,1692))
    mgemm3(U(uAGG), U(uW2X), ws+bB2, gate + 846, 846, 896, KXP, GST, 0, nullptr, stream);
    gru2_combine<<<NB, 128, 0, stream>>>(gate, U(uXIN), U(uAGG));
    // out-GEMM; for l<2 epilogue also refreshes xin cols 0..255 (pos/ub cols persist)
    mgemm3(U(uAGG), uGW[l], gb[l], XL[l], 256, 256, KXP, 256, 1,
           (l < 2) ? U(uXIN) : nullptr, stream);
  }

  // --- epilogue ---
  sum_ln<<<NB, 256, 0, stream>>>(XL[0], XL[1], XL[2], ln_g, ln_b, ws+bYF);  // in-place on x1
  build_cat<<<NB, 128, 0, stream>>>(ws+bRNN, ws+bYF, uCAT, 1);
  mgemm3(uCAT, U(uL2), lin2_b, (float*)d_out, 256, 256, 512, 256, 1, nullptr, stream);
}